// Round 4
// baseline (526.072 us; speedup 1.0000x reference)
//
#include <hip/hip_runtime.h>
#include <math.h>

// MultiHeadAttention: B=2, S=2048, D=2048, H=16, dh=128, causal.
// v4: QKV gemm 128x256 tile with 64x128 waves (4x8 acc, less LDS/FLOP),
// attention with 32 Q-rows/wave (68 MFMA per softmax round).

typedef _Float16 half8 __attribute__((ext_vector_type(8)));
typedef _Float16 half4v __attribute__((ext_vector_type(4)));
typedef float f32x4 __attribute__((ext_vector_type(4)));

__device__ __forceinline__ void gl_lds16(const void* g, void* l) {
  __builtin_amdgcn_global_load_lds(
      (const __attribute__((address_space(1))) unsigned int*)g,
      (__attribute__((address_space(3))) unsigned int*)l, 16, 0, 0);
}

// ---------------- cast fp32 -> fp16 ----------------
__global__ void cast_f32_f16(const float* __restrict__ src, _Float16* __restrict__ dst, int n4) {
  int i = blockIdx.x * blockDim.x + threadIdx.x;
  if (i >= n4) return;
  float4 v = reinterpret_cast<const float4*>(src)[i];
  half4v o;
  o[0] = (_Float16)v.x; o[1] = (_Float16)v.y; o[2] = (_Float16)v.z; o[3] = (_Float16)v.w;
  reinterpret_cast<half4v*>(dst)[i] = o;
}

__global__ void cast_w(const float* __restrict__ w0, const float* __restrict__ w1,
                       const float* __restrict__ w2, const float* __restrict__ w3,
                       _Float16* __restrict__ wdst) {
  const float* s = blockIdx.y == 0 ? w0 : blockIdx.y == 1 ? w1 : blockIdx.y == 2 ? w2 : w3;
  int i = blockIdx.x * blockDim.x + threadIdx.x;
  float4 v = reinterpret_cast<const float4*>(s)[i];
  half4v o;
  o[0] = (_Float16)v.x; o[1] = (_Float16)v.y; o[2] = (_Float16)v.z; o[3] = (_Float16)v.w;
  reinterpret_cast<half4v*>(wdst)[(size_t)blockIdx.y * 1048576 + i] = o;
}

// ---------------- big-tile GEMM: 128(M) x 256(N), 4 waves of 64x128 ----------------
// Wave acc = 4x8 of 16x16: 32 MFMA per K-step vs 12 LDS fragment reads
// (2.67 MFMA/frag vs 2.0 for 64x64) and half the barriers per FLOP.
template <bool OUT_F32>
__global__ __launch_bounds__(256, 2) void gemm_bt_big(
    const _Float16* __restrict__ A,   // M x K
    const _Float16* __restrict__ B,   // N x K
    const float* __restrict__ b0, const float* __restrict__ b1,
    const float* __restrict__ b2,     // bias for col/2048 == 0,1,2
    void* __restrict__ Cout,          // M x N
    int M, int N, int K) {
  __shared__ _Float16 As[2][4096];   // 128x32 per buf (8 KB)
  __shared__ _Float16 Bs[2][8192];   // 256x32 per buf (16 KB)
  const int bm = blockIdx.y * 128, bn = blockIdx.x * 256;
  const int tid = threadIdx.x;
  const int wave = tid >> 6, lane = tid & 63;
  const int quad = lane >> 4, l16 = lane & 15;
  const int ih = wave >> 1, jh = wave & 1;  // wave's M-half (64) / N-half (128)

  // staging decode: p=0,1 -> A chunks [0,512); p=2..5 -> B chunks [0,1024)
  const _Float16* gsrc[6];
  int lofs[6];
#pragma unroll
  for (int p = 0; p < 6; ++p) {
    if (p < 2) {
      int c = p * 256 + tid;
      int cl16 = c & 15, cqd = (c >> 4) & 3, ci = (c >> 6) & 3, ch = c >> 8;
      gsrc[p] = A + (size_t)(bm + ch * 64 + ci * 16 + cl16) * K + cqd * 8;
      lofs[p] = c * 8;
    } else {
      int c = (p - 2) * 256 + tid;
      int cl16 = c & 15, cqd = (c >> 4) & 3, cn = (c >> 6) & 7, cjh = (c >> 9) & 1;
      gsrc[p] = B + (size_t)(bn + cjh * 128 + cn * 16 + cl16) * K + cqd * 8;
      lofs[p] = c * 8;
    }
  }

  f32x4 acc[4][8];
#pragma unroll
  for (int i = 0; i < 4; ++i)
#pragma unroll
    for (int n = 0; n < 8; ++n) acc[i][n] = f32x4{0.f, 0.f, 0.f, 0.f};

  // prologue: stage k-step 0 into buf 0
#pragma unroll
  for (int p = 0; p < 6; ++p)
    gl_lds16(gsrc[p], (p < 2 ? &As[0][lofs[p]] : &Bs[0][lofs[p]]));

  const int nit = K >> 5;
  for (int it = 0; it < nit; ++it) {
    __syncthreads();  // drains vmcnt: buf[it&1] staged; prior reads done
    const int cur = it & 1;
    if (it + 1 < nit) {
      const int nxt = cur ^ 1, ko = (it + 1) * 32;
#pragma unroll
      for (int p = 0; p < 6; ++p)
        gl_lds16(gsrc[p] + ko, (p < 2 ? &As[nxt][lofs[p]] : &Bs[nxt][lofs[p]]));
    }
    half8 af[4], bf[8];
#pragma unroll
    for (int i = 0; i < 4; ++i)
      af[i] = *reinterpret_cast<const half8*>(&As[cur][((ih * 4 + i) * 4 + quad) * 128 + l16 * 8]);
#pragma unroll
    for (int n = 0; n < 8; ++n)
      bf[n] = *reinterpret_cast<const half8*>(&Bs[cur][((jh * 8 + n) * 4 + quad) * 128 + l16 * 8]);
#pragma unroll
    for (int i = 0; i < 4; ++i)
#pragma unroll
      for (int n = 0; n < 8; ++n)
        acc[i][n] = __builtin_amdgcn_mfma_f32_16x16x32_f16(af[i], bf[n], acc[i][n], 0, 0, 0);
  }

  const int wm = ih * 64, wn = jh * 128;
#pragma unroll
  for (int n = 0; n < 8; ++n) {
    const int gc = bn + wn + n * 16 + l16;
    const float* bp = (gc < 2048) ? b0 : (gc < 4096 ? b1 : b2);
    const float bz = bp[gc & 2047];
#pragma unroll
    for (int i = 0; i < 4; ++i) {
#pragma unroll
      for (int r = 0; r < 4; ++r) {
        const int gr = bm + wm + i * 16 + quad * 4 + r;
        float v = acc[i][n][r] + bz;
        if (OUT_F32)
          reinterpret_cast<float*>(Cout)[(size_t)gr * N + gc] = v;
        else
          reinterpret_cast<_Float16*>(Cout)[(size_t)gr * N + gc] = (_Float16)v;
      }
    }
  }
}

// ---------------- GEMM 128x128 (kept for O-projection) ----------------
template <bool OUT_F32>
__global__ __launch_bounds__(256, 2) void gemm_bt(
    const _Float16* __restrict__ A, const _Float16* __restrict__ B,
    const float* __restrict__ b0, const float* __restrict__ b1,
    const float* __restrict__ b2, void* __restrict__ Cout, int M, int N, int K) {
  __shared__ _Float16 As[2][4096];
  __shared__ _Float16 Bs[2][4096];
  const int bm = blockIdx.y * 128, bn = blockIdx.x * 128;
  const int tid = threadIdx.x;
  const int wave = tid >> 6, lane = tid & 63;
  const int quad = lane >> 4, l16 = lane & 15;
  const int hh = wave >> 1, gg = wave & 1;

  const _Float16* gsrc[4];
  int lofs[4];
#pragma unroll
  for (int p = 0; p < 4; ++p) {
    int c = ((p & 1) * 256 + tid) & 511;
    int cl16 = c & 15, cqd = (c >> 4) & 3, ci = (c >> 6) & 3, ch = c >> 8;
    int grow = ch * 64 + ci * 16 + cl16;
    gsrc[p] = (p < 2 ? A + (size_t)(bm + grow) * K : B + (size_t)(bn + grow) * K) + cqd * 8;
    lofs[p] = c * 8;
  }

  f32x4 acc[4][4];
#pragma unroll
  for (int i = 0; i < 4; ++i)
#pragma unroll
    for (int n = 0; n < 4; ++n) acc[i][n] = f32x4{0.f, 0.f, 0.f, 0.f};

#pragma unroll
  for (int p = 0; p < 4; ++p)
    gl_lds16(gsrc[p], (p < 2 ? &As[0][lofs[p]] : &Bs[0][lofs[p]]));

  const int nit = K >> 5;
  for (int it = 0; it < nit; ++it) {
    __syncthreads();
    const int cur = it & 1;
    if (it + 1 < nit) {
      const int nxt = cur ^ 1, ko = (it + 1) * 32;
#pragma unroll
      for (int p = 0; p < 4; ++p)
        gl_lds16(gsrc[p] + ko, (p < 2 ? &As[nxt][lofs[p]] : &Bs[nxt][lofs[p]]));
    }
    half8 af[4], bf[4];
#pragma unroll
    for (int i = 0; i < 4; ++i)
      af[i] = *reinterpret_cast<const half8*>(&As[cur][((hh * 4 + i) * 4 + quad) * 128 + l16 * 8]);
#pragma unroll
    for (int n = 0; n < 4; ++n)
      bf[n] = *reinterpret_cast<const half8*>(&Bs[cur][((gg * 4 + n) * 4 + quad) * 128 + l16 * 8]);
#pragma unroll
    for (int i = 0; i < 4; ++i)
#pragma unroll
      for (int n = 0; n < 4; ++n)
        acc[i][n] = __builtin_amdgcn_mfma_f32_16x16x32_f16(af[i], bf[n], acc[i][n], 0, 0, 0);
  }

  const int wm = hh * 64, wn = gg * 64;
#pragma unroll
  for (int n = 0; n < 4; ++n) {
    const int gc = bn + wn + n * 16 + l16;
    const float* bp = (gc < 2048) ? b0 : (gc < 4096 ? b1 : b2);
    const float bz = bp[gc & 2047];
#pragma unroll
    for (int i = 0; i < 4; ++i) {
#pragma unroll
      for (int r = 0; r < 4; ++r) {
        const int gr = bm + wm + i * 16 + quad * 4 + r;
        float v = acc[i][n][r] + bz;
        if (OUT_F32)
          reinterpret_cast<float*>(Cout)[(size_t)gr * N + gc] = v;
        else
          reinterpret_cast<_Float16*>(Cout)[(size_t)gr * N + gc] = (_Float16)v;
      }
    }
  }
}

// ---------------- RoPE in-place on fused qkv (rows stride 6144) ----------------
__global__ void rope_inplace(_Float16* __restrict__ qkv, int ngroups) {
  int idx = blockIdx.x * blockDim.x + threadIdx.x;
  if (idx >= ngroups) return;
  int m = idx >> 8;
  int g = idx & 255;
  int s = m & 2047;
  const float scale = 0.088388347648318447f;  // 1/sqrt(128), folded into q
  size_t base = (size_t)m * 6144 + g * 8;
  half8 qv = *reinterpret_cast<const half8*>(qkv + base);
  half8 kv = *reinterpret_cast<const half8*>(qkv + base + 2048);
  half8 qo, ko;
#pragma unroll
  for (int j = 0; j < 4; ++j) {
    int i = (g * 4 + j) & 63;
    float ang = (float)s * exp2f(-0.2076205059304601f * (float)i);
    float sn, cs;
    __sincosf(ang, &sn, &cs);
    float e = (float)qv[j * 2], o = (float)qv[j * 2 + 1];
    qo[j * 2]     = (_Float16)((e * cs - o * sn) * scale);
    qo[j * 2 + 1] = (_Float16)((o * cs + e * sn) * scale);
    e = (float)kv[j * 2]; o = (float)kv[j * 2 + 1];
    ko[j * 2]     = (_Float16)(e * cs - o * sn);
    ko[j * 2 + 1] = (_Float16)(o * cs + e * sn);
  }
  *reinterpret_cast<half8*>(qkv + base) = qo;
  *reinterpret_cast<half8*>(qkv + base + 2048) = ko;
}

// ---------------- V transpose: qkv v-cols (stride 6144) -> (B,H,dh,S) ----------------
__global__ __launch_bounds__(256) void transpose_v(const _Float16* __restrict__ qkv,
                                                   _Float16* __restrict__ vt) {
  __shared__ _Float16 t[64][72];
  const int s0 = blockIdx.x * 64;
  const int d0 = blockIdx.y * 64;
  const int bh = blockIdx.z;
  const int b = bh >> 4, h = bh & 15;
  const int tid = threadIdx.x;
#pragma unroll
  for (int p = 0; p < 2; ++p) {
    int chunk = p * 256 + tid;
    int r = chunk >> 3, c8 = (chunk & 7) * 8;
    *reinterpret_cast<half8*>(&t[r][c8]) = *reinterpret_cast<const half8*>(
        &qkv[(size_t)(b * 2048 + s0 + r) * 6144 + 4096 + h * 128 + d0 + c8]);
  }
  __syncthreads();
#pragma unroll
  for (int p = 0; p < 2; ++p) {
    int chunk = p * 256 + tid;
    int dr = chunk >> 3, c8 = (chunk & 7) * 8;
    half8 o;
#pragma unroll
    for (int j = 0; j < 8; ++j) o[j] = t[c8 + j][dr];
    *reinterpret_cast<half8*>(&vt[(size_t)(bh * 128 + d0 + dr) * 2048 + s0 + c8]) = o;
  }
}

// ---------------- Flash attention (causal), 32 Q-rows/wave ----------------
// Block: 128 Q-rows x one (b,h), 4 waves x 32 rows (2 row-tiles). 64-key
// dbuf LDS tiles; 68 MFMA per softmax round. Heavy-first 512-block grid.
__global__ __launch_bounds__(256, 2) void attn_kernel(
    const _Float16* __restrict__ QKV,  // (4096, 6144): q|k|v
    const _Float16* __restrict__ VT,   // (32, 128, 2048)
    _Float16* __restrict__ ctx) {      // (4096, 2048)
  constexpr int LD = 6144, S = 2048;
  __shared__ _Float16 Ks[2][8192];   // 32 KB
  __shared__ _Float16 Vs[2][8192];   // 32 KB
  __shared__ _Float16 P[4][16][80];  // 10 KB, reused across the 2 row-tiles
  const int bid = blockIdx.x;
  const int bh = bid & 31;
  const int qt = 15 - (bid >> 5);    // heavy-first
  const int b = bh >> 4, h = bh & 15;
  const int tid = threadIdx.x;
  const int wv = tid >> 6, lane = tid & 63;
  const int quad = lane >> 4, l16 = lane & 15;
  const int q0 = qt * 128 + wv * 32;

  // Q fragments (pre-scaled in rope): 2 row-tiles x 4 k-steps
  half8 aq[2][4];
#pragma unroll
  for (int rt = 0; rt < 2; ++rt)
#pragma unroll
    for (int ks = 0; ks < 4; ++ks)
      aq[rt][ks] = *reinterpret_cast<const half8*>(
          QKV + (size_t)(b * S + q0 + rt * 16 + l16) * LD + h * 128 + ks * 32 + quad * 8);

  // staging addresses (K: rows=keys stride LD; V: rows=dh stride S)
  const _Float16* gk[4];
  const _Float16* gv[4];
  int lofs[4];
#pragma unroll
  for (int p = 0; p < 4; ++p) {
    int c = p * 256 + tid;  // [0,1024)
    int cl16 = c & 15, cqd = (c >> 4) & 3;
    int cks = (c >> 6) & 3, cf = c >> 8;
    gk[p] = QKV + (size_t)(b * S + cf * 16 + cl16) * LD + 2048 + h * 128 + cks * 32 + cqd * 8;
    int ckv = (c >> 6) & 1, ct = c >> 7;
    gv[p] = VT + (size_t)(bh * 128 + ct * 16 + cl16) * S + ckv * 32 + cqd * 8;
    lofs[p] = c * 8;
  }

  f32x4 acc[2][8];
#pragma unroll
  for (int rt = 0; rt < 2; ++rt)
#pragma unroll
    for (int t = 0; t < 8; ++t) acc[rt][t] = f32x4{0.f, 0.f, 0.f, 0.f};
  f32x4 lacc[2] = {f32x4{0.f, 0.f, 0.f, 0.f}, f32x4{0.f, 0.f, 0.f, 0.f}};
  float m_i[2][4];
#pragma unroll
  for (int rt = 0; rt < 2; ++rt)
#pragma unroll
    for (int r = 0; r < 4; ++r) m_i[rt][r] = -INFINITY;

  half8 ones;
#pragma unroll
  for (int j = 0; j < 8; ++j) ones[j] = (_Float16)1.0f;

  // prologue: stage tile 0 into buf 0
#pragma unroll
  for (int p = 0; p < 4; ++p) gl_lds16(gk[p], &Ks[0][lofs[p]]);
#pragma unroll
  for (int p = 0; p < 4; ++p) gl_lds16(gv[p], &Vs[0][lofs[p]]);

  const int nkt = 2 * (qt + 1);
  for (int j = 0; j < nkt; ++j) {
    __syncthreads();  // buf[j&1] staged; prior tile's reads complete
    const int cur = j & 1;
    if (j + 1 < nkt) {
      const size_t ko = (size_t)(j + 1) * 64 * LD;
      const int vo = (j + 1) * 64;
#pragma unroll
      for (int p = 0; p < 4; ++p) gl_lds16(gk[p] + ko, &Ks[cur ^ 1][lofs[p]]);
#pragma unroll
      for (int p = 0; p < 4; ++p) gl_lds16(gv[p] + vo, &Vs[cur ^ 1][lofs[p]]);
    }
    const int key0 = j * 64;
    if (key0 > q0 + 31) continue;  // fully masked for this wave (still did barrier)

    // ---- QK^T: 32 rows x 64 keys (32 MFMA) ----
    f32x4 sf[2][4];
#pragma unroll
    for (int rt = 0; rt < 2; ++rt)
#pragma unroll
      for (int f = 0; f < 4; ++f) sf[rt][f] = f32x4{0.f, 0.f, 0.f, 0.f};
#pragma unroll
    for (int f = 0; f < 4; ++f)
#pragma unroll
      for (int ks = 0; ks < 4; ++ks) {
        half8 bk = *reinterpret_cast<const half8*>(&Ks[cur][((f * 4 + ks) * 4 + quad) * 128 + l16 * 8]);
        sf[0][f] = __builtin_amdgcn_mfma_f32_16x16x32_f16(aq[0][ks], bk, sf[0][f], 0, 0, 0);
        sf[1][f] = __builtin_amdgcn_mfma_f32_16x16x32_f16(aq[1][ks], bk, sf[1][f], 0, 0, 0);
      }
    // ---- causal mask (only near-diagonal tiles) ----
    if (key0 + 63 > q0) {
#pragma unroll
      for (int rt = 0; rt < 2; ++rt)
#pragma unroll
        for (int f = 0; f < 4; ++f) {
          const int key = key0 + f * 16 + l16;
#pragma unroll
          for (int r = 0; r < 4; ++r) {
            const int row = q0 + rt * 16 + quad * 4 + r;
            sf[rt][f][r] = (key <= row) ? sf[rt][f][r] : -1e30f;
          }
        }
    }
    // ---- online softmax + P (C->A layout via per-wave LDS, reused per rt) ----
    float alpha[2][4];
    half8 pa[2][2];
#pragma unroll
    for (int rt = 0; rt < 2; ++rt) {
#pragma unroll
      for (int r = 0; r < 4; ++r) {
        float tm = fmaxf(fmaxf(sf[rt][0][r], sf[rt][1][r]), fmaxf(sf[rt][2][r], sf[rt][3][r]));
        tm = fmaxf(tm, __shfl_xor(tm, 1));
        tm = fmaxf(tm, __shfl_xor(tm, 2));
        tm = fmaxf(tm, __shfl_xor(tm, 4));
        tm = fmaxf(tm, __shfl_xor(tm, 8));
        const float mn = fmaxf(m_i[rt][r], tm);
        alpha[rt][r] = __expf(m_i[rt][r] - mn);
        m_i[rt][r] = mn;
      }
#pragma unroll
      for (int f = 0; f < 4; ++f)
#pragma unroll
        for (int r = 0; r < 4; ++r)
          P[wv][quad * 4 + r][f * 16 + l16] = (_Float16)__expf(sf[rt][f][r] - m_i[rt][r]);
      // wave-local LDS: write->read ordering is in-order on the DS pipe
      pa[rt][0] = *reinterpret_cast<const half8*>(&P[wv][l16][quad * 8]);
      pa[rt][1] = *reinterpret_cast<const half8*>(&P[wv][l16][32 + quad * 8]);
    }
    // ---- rescale + PV (32 MFMA, V frags shared across rt) + l-sums ----
#pragma unroll
    for (int rt = 0; rt < 2; ++rt) {
#pragma unroll
      for (int t = 0; t < 8; ++t)
#pragma unroll
        for (int r = 0; r < 4; ++r) acc[rt][t][r] *= alpha[rt][r];
#pragma unroll
      for (int r = 0; r < 4; ++r) lacc[rt][r] *= alpha[rt][r];
    }
#pragma unroll
    for (int t = 0; t < 8; ++t) {
      half8 bv0 = *reinterpret_cast<const half8*>(&Vs[cur][((t * 2 + 0) * 4 + quad) * 128 + l16 * 8]);
      half8 bv1 = *reinterpret_cast<const half8*>(&Vs[cur][((t * 2 + 1) * 4 + quad) * 128 + l16 * 8]);
#pragma unroll
      for (int rt = 0; rt < 2; ++rt) {
        acc[rt][t] = __builtin_amdgcn_mfma_f32_16x16x32_f16(pa[rt][0], bv0, acc[rt][t], 0, 0, 0);
        acc[rt][t] = __builtin_amdgcn_mfma_f32_16x16x32_f16(pa[rt][1], bv1, acc[rt][t], 0, 0, 0);
      }
    }
#pragma unroll
    for (int rt = 0; rt < 2; ++rt) {
      lacc[rt] = __builtin_amdgcn_mfma_f32_16x16x32_f16(pa[rt][0], ones, lacc[rt], 0, 0, 0);
      lacc[rt] = __builtin_amdgcn_mfma_f32_16x16x32_f16(pa[rt][1], ones, lacc[rt], 0, 0, 0);
    }
  }

  // ---- epilogue ----
#pragma unroll
  for (int rt = 0; rt < 2; ++rt) {
    float inv[4];
#pragma unroll
    for (int r = 0; r < 4; ++r) inv[r] = 1.0f / lacc[rt][r];
#pragma unroll
    for (int t = 0; t < 8; ++t)
#pragma unroll
      for (int r = 0; r < 4; ++r)
        ctx[(size_t)(b * S + q0 + rt * 16 + quad * 4 + r) * 2048 + h * 128 + t * 16 + l16] =
            (_Float16)(acc[rt][t][r] * inv[r]);
  }
}

// ---------------- launcher ----------------
extern "C" void kernel_launch(void* const* d_in, const int* in_sizes, int n_in,
                              void* d_out, int out_size, void* d_ws, size_t ws_size,
                              hipStream_t stream) {
  const float* x  = (const float*)d_in[0];
  const float* wq = (const float*)d_in[1];
  const float* bq = (const float*)d_in[2];
  const float* wk = (const float*)d_in[3];
  const float* bk = (const float*)d_in[4];
  const float* wv = (const float*)d_in[5];
  const float* bv = (const float*)d_in[6];
  const float* wo = (const float*)d_in[7];
  const float* bo = (const float*)d_in[8];
  // d_in[9] = mask: causal triu(k=1), hardcoded in attn_kernel.

  _Float16* W      = (_Float16*)d_ws;
  _Float16* xh     = W;                  // 16 MB (4096,2048)
  _Float16* wqkvh  = xh + 8388608;       // 24 MB (6144,2048) wq|wk|wv
  _Float16* woh    = wqkvh + 12582912;   // 8 MB
  _Float16* qkvlin = woh + 4194304;      // 48 MB (4096,6144)
  _Float16* vT     = xh;                 // reuse: x dead after QKV gemm
  _Float16* ctx    = wqkvh;              // reuse: wqkv dead after QKV gemm

  cast_f32_f16<<<8192, 256, 0, stream>>>(x, xh, 2097152);
  cast_w<<<dim3(4096, 4), 256, 0, stream>>>(wq, wk, wv, wo, wqkvh);

  // fused QKV gemm: (4096,2048) x (6144,2048)^T -> (4096,6144)
  gemm_bt_big<false><<<dim3(24, 32), 256, 0, stream>>>(xh, wqkvh, bq, bk, bv, qkvlin,
                                                       4096, 6144, 2048);

  rope_inplace<<<4096, 256, 0, stream>>>(qkvlin, 1048576);
  transpose_v<<<dim3(32, 2, 32), 256, 0, stream>>>(qkvlin, vT);
  attn_kernel<<<512, 256, 0, stream>>>(qkvlin, vT, ctx);

  // output gemm: (4096,2048) x (2048,2048)^T -> fp32 out
  gemm_bt<true><<<dim3(16, 32), 256, 0, stream>>>(ctx, woh, bo, bo, bo, (float*)d_out,
                                                  4096, 2048, 2048);
}